// Round 1
// baseline (99.212 us; speedup 1.0000x reference)
//
#include <hip/hip_runtime.h>

// DNM dendritic layer: out[b,o] = max(0, 0.25*S - 0.05),
//   S = sum_{m,i} relu(x[b,i]*W[o,m,i] - q[o,m,i])
// B=512, OUT=128, M=8, IN=512, fp32. VALU-bound (relu inside reduction => no MFMA).
// Floor: 3 VALU ops/elem * 2.68e8 elems / 78.6e12 lane-ops/s ~= 10.2 us.

#define BB   512
#define OUTN 128
#define MM   8
#define INN  512

// Block: 256 threads = 4 waves. One o per block, 64 b's (16 per wave).
// Grid: 128 o * 8 b-groups = 1024 blocks.
__global__ __launch_bounds__(256, 2) void dnm_kernel(
    const float* __restrict__ x,   // [B, IN]
    const float* __restrict__ W,   // [OUT, M, IN]
    const float* __restrict__ q,   // [OUT, M, IN]
    float* __restrict__ out)       // [B, OUT]
{
    __shared__ float lds_w[MM * INN];
    __shared__ float lds_q[MM * INN];

    const int tid  = threadIdx.x;
    const int o    = blockIdx.x >> 3;
    const int bgrp = blockIdx.x & 7;
    const int wave = tid >> 6;
    const int lane = tid & 63;
    const int b0   = bgrp * 64 + wave * 16;

    // Stage W[o,:,:] and q[o,:,:] (32 KB) into LDS, coalesced float4.
    {
        const float4* Wg = (const float4*)(W + (size_t)o * MM * INN);
        const float4* qg = (const float4*)(q + (size_t)o * MM * INN);
        float4* lw = (float4*)lds_w;
        float4* lq = (float4*)lds_q;
        #pragma unroll
        for (int j = 0; j < (MM * INN / 4); j += 256) {
            lw[j + tid] = Wg[j + tid];
            lq[j + tid] = qg[j + tid];
        }
    }
    __syncthreads();

    float acc[16];
    #pragma unroll
    for (int b = 0; b < 16; ++b) acc[b] = 0.0f;

    // Lanes span i: 64 lanes * 4 floats = 256 i per chunk, 2 chunks cover IN=512.
    #pragma unroll
    for (int chunk = 0; chunk < 2; ++chunk) {
        const int i = chunk * 256 + lane * 4;

        // Load x for all 16 b's once per chunk; reused across all 8 m's.
        float4 xv[16];
        #pragma unroll
        for (int b = 0; b < 16; ++b)
            xv[b] = *(const float4*)(x + (size_t)(b0 + b) * INN + i);

        #pragma unroll
        for (int m = 0; m < MM; ++m) {
            const float4 w4 = *(const float4*)(lds_w + m * INN + i);
            const float4 q4 = *(const float4*)(lds_q + m * INN + i);
            #pragma unroll
            for (int b = 0; b < 16; ++b) {
                // 4 fma + 4 max + 4 add = 12 VALU per 4 elements (3/elem floor)
                float t0 = fmaxf(xv[b].x * w4.x - q4.x, 0.0f);
                float t1 = fmaxf(xv[b].y * w4.y - q4.y, 0.0f);
                float t2 = fmaxf(xv[b].z * w4.z - q4.z, 0.0f);
                float t3 = fmaxf(xv[b].w * w4.w - q4.w, 0.0f);
                acc[b] += (t0 + t1) + (t2 + t3);
            }
        }
    }

    // Butterfly-reduce each acc[b] across the 64 lanes; lane b writes (b0+b, o).
    #pragma unroll
    for (int b = 0; b < 16; ++b) {
        float v = acc[b];
        v += __shfl_xor(v, 1, 64);
        v += __shfl_xor(v, 2, 64);
        v += __shfl_xor(v, 4, 64);
        v += __shfl_xor(v, 8, 64);
        v += __shfl_xor(v, 16, 64);
        v += __shfl_xor(v, 32, 64);
        if (lane == b) {
            float r = 0.25f * v - 0.05f;   // K*K*S - K*QS
            out[(size_t)(b0 + b) * OUTN + o] = fmaxf(r, 0.0f);
        }
    }
}

extern "C" void kernel_launch(void* const* d_in, const int* in_sizes, int n_in,
                              void* d_out, int out_size, void* d_ws, size_t ws_size,
                              hipStream_t stream) {
    const float* x = (const float*)d_in[0];
    const float* W = (const float*)d_in[1];
    const float* q = (const float*)d_in[2];
    float* out = (float*)d_out;
    dim3 grid(OUTN * 8);   // 128 o * 8 b-groups
    dim3 block(256);
    dnm_kernel<<<grid, block, 0, stream>>>(x, W, q, out);
}